// Round 8
// baseline (395.490 us; speedup 1.0000x reference)
//
#include <hip/hip_runtime.h>

#define N_NODES 10000
#define N_EDGES 20000
#define DIM 64
#define NF 14
#define NB 200
#define NPG 50      // nodes per graph (batch = repeat(arange(200), 50))
#define STEPS 4
#define S2S_STEPS 3

typedef short short8 __attribute__((ext_vector_type(8)));
typedef float f32x4 __attribute__((ext_vector_type(4)));
typedef unsigned short u16;

__device__ __forceinline__ u16 f2bf(float f) {
  unsigned u = __float_as_uint(f);
  u += 0x7FFFu + ((u >> 16) & 1u);   // RNE
  return (u16)(u >> 16);
}
__device__ __forceinline__ float lrelu(float v) { return v > 0.f ? v : 0.01f * v; }
__device__ __forceinline__ float sigm(float x) { return 1.f / (1.f + expf(-x)); }

// Fused preprocessing, block-range split:
//  [0,2500):       out0 = leaky_relu(x @ lin0_w + lin0_b)             [N,64]
//  [2500,12500):   h1 = bf16(leaky_relu(edge_attr @ enet_w1 + b1))    [E,128]
//  [12500,12564):  W2T[o][i][k] = bf16(w2[k][i*64+o])  (LDS-tile transpose)
//  [12564,12612):  wihT, whhT (GRU weight transposes)
//  [12612,12691):  cnt = scatter-count of dst
__global__ __launch_bounds__(256) void k_prep_all(
    const float* __restrict__ x, const float* __restrict__ lin0_w,
    const float* __restrict__ lin0_b, float* __restrict__ out0,
    const float* __restrict__ ea, const float* __restrict__ w1,
    const float* __restrict__ b1, u16* __restrict__ h1,
    const float* __restrict__ w2,
    const float* __restrict__ wih, const float* __restrict__ whh,
    u16* __restrict__ W2T,
    float* __restrict__ wihT, float* __restrict__ whhT,
    const int* __restrict__ dst, float* __restrict__ cnt) {
  const int b = blockIdx.x, tid = threadIdx.x;
  if (b < 2500) {                      // lin0: 2500*256 = N*64 exact
    int t = b * 256 + tid;
    int n = t >> 6, o = t & 63;
    float acc = lin0_b[o];
    #pragma unroll
    for (int f = 0; f < NF; ++f) acc += x[n * NF + f] * lin0_w[f * DIM + o];
    out0[t] = lrelu(acc);
  } else if (b < 12500) {              // h1: 10000*256 = E*128 exact
    int t = (b - 2500) * 256 + tid;
    int e = t >> 7, k = t & 127;
    float acc = b1[k];
    #pragma unroll
    for (int f = 0; f < 4; ++f) acc += ea[e * 4 + f] * w1[f * 128 + k];
    h1[t] = f2bf(lrelu(acc));
  } else if (b < 12564) {              // W2T transpose: 64 blocks, one per i
    __shared__ float tile[128][65];    // +1 pad
    int i = b - 12500;
    #pragma unroll
    for (int rep = 0; rep < 32; ++rep) {
      int idx = rep * 256 + tid;       // 8192 = 128k * 64o
      int k = idx >> 6, o = idx & 63;
      tile[k][o] = w2[(size_t)k * 4096 + i * 64 + o];   // coalesced rows
    }
    __syncthreads();
    int o = tid >> 2, kc = (tid & 3) * 32;
    u16* d = W2T + (size_t)o * 8192 + i * 128 + kc;
    #pragma unroll
    for (int j = 0; j < 32; ++j) d[j] = f2bf(tile[kc + j][o]);
  } else if (b < 12612) {              // GRU weight transposes: 48*256 = 12288
    int t = (b - 12564) * 256 + tid;
    int p = t >> 12, rem = t & 4095, i = rem >> 6, o = rem & 63;
    int g = p * 64 + o;
    wihT[t] = wih[g * 64 + i];
    whhT[t] = whh[g * 64 + i];
  } else {                             // cnt
    int t = (b - 12612) * 256 + tid;
    if (t < N_EDGES) atomicAdd(cnt + dst[t], 1.f);
  }
}

// Fused edge message: msg[e,o] = sum_i x[e,i]*(U_i[e,o] + b2[i*64+o]),
// U_i = h1[e,:] @ W2[:, i*64+o] computed on the fly via MFMA (never stored).
// Block = 64 edges x 64 o; wave wv owns 16 o-cols. A-frags (h1) are
// i-invariant -> hoisted into 16 VGPRs. W2T (1 MB) is L2-pinned; per-i
// B-frags are 4 x b128 global loads (16 full 64B lines each). Per-row scale
// x[e,i] applied to the f32 MFMA output (rows scale independently).
// Scatter: atomicAdd into agg[dst[e]*64+o].
__global__ __launch_bounds__(256) void k_msgemm(
    const u16* __restrict__ h1,      // [20032][128] bf16 (padded)
    const u16* __restrict__ W2T,     // [64 o][64 i][128 k] bf16
    const float* __restrict__ b2,    // [4096] = [i*64+o]
    const float* __restrict__ out,   // [10000][64] f32
    const int* __restrict__ src, const int* __restrict__ dst,
    float* __restrict__ agg) {
  __shared__ __align__(16) u16 h1s[64 * 128];     // 16 KB, XOR-swizzled
  __shared__ __align__(16) float xT[64 * 64];     // 16 KB, [i][e]
  __shared__ int s_dst[64];
  const int tid = threadIdx.x;
  const int e0 = blockIdx.x * 64;
  if (tid < 64) {
    int ge = e0 + tid;
    s_dst[tid] = (ge < N_EDGES) ? dst[ge] : 0;
  }
  // stage h1 tile: LDS slot s of row r holds source granule s^(r&7)
  #pragma unroll
  for (int it = 0; it < 4; ++it) {
    int c = it * 256 + tid;          // 0..1023
    int r = c >> 4;                  // 0..63
    int g = (c & 15) ^ (r & 7);
    *(short8*)(h1s + r * 128 + (c & 15) * 8) =
        *(const short8*)(h1 + (size_t)(e0 + r) * 128 + g * 8);
  }
  // gather x^T = out[src[e]] transposed to [i][e]
  {
    int e = tid & 63, part = tid >> 6;
    int ge = e0 + e;
    int s = (ge < N_EDGES) ? src[ge] : 0;
    const float* orow = out + (size_t)s * 64 + part * 16;
    #pragma unroll
    for (int q = 0; q < 4; ++q) {
      f32x4 v = *(const f32x4*)(orow + q * 4);
      int ib = part * 16 + q * 4;
      xT[(ib + 0) * 64 + e] = v[0];
      xT[(ib + 1) * 64 + e] = v[1];
      xT[(ib + 2) * 64 + e] = v[2];
      xT[(ib + 3) * 64 + e] = v[3];
    }
  }
  __syncthreads();
  const int lane = tid & 63, wv = tid >> 6, lo = lane & 15, hi = lane >> 4;
  // hoist A-frags (h1 rows, i-invariant): 16 x short8
  short8 a[4][4];
  #pragma unroll
  for (int mf = 0; mf < 4; ++mf)
    #pragma unroll
    for (int kk = 0; kk < 4; ++kk)
      a[mf][kk] = *(const short8*)(h1s + (mf * 16 + lo) * 128 +
                                   (((kk * 4 + hi) ^ (lo & 7)) * 8));
  const u16* bbase = W2T + (size_t)(wv * 16 + lo) * 8192 + hi * 8;
  const float* b2base = b2 + wv * 16 + lo;
  f32x4 msg[4];
  #pragma unroll
  for (int mf = 0; mf < 4; ++mf) msg[mf] = (f32x4){0.f, 0.f, 0.f, 0.f};
  #pragma unroll 2
  for (int i = 0; i < 64; ++i) {
    short8 b0 = *(const short8*)(bbase + i * 128);
    short8 b1 = *(const short8*)(bbase + i * 128 + 32);
    short8 b2f = *(const short8*)(bbase + i * 128 + 64);
    short8 b3 = *(const short8*)(bbase + i * 128 + 96);
    float bv = b2base[(size_t)i * 64];
    #pragma unroll
    for (int mf = 0; mf < 4; ++mf) {
      f32x4 xv = *(const f32x4*)(xT + i * 64 + mf * 16 + hi * 4);
      f32x4 u = (f32x4){0.f, 0.f, 0.f, 0.f};
      u = __builtin_amdgcn_mfma_f32_16x16x32_bf16(a[mf][0], b0, u, 0, 0, 0);
      u = __builtin_amdgcn_mfma_f32_16x16x32_bf16(a[mf][1], b1, u, 0, 0, 0);
      u = __builtin_amdgcn_mfma_f32_16x16x32_bf16(a[mf][2], b2f, u, 0, 0, 0);
      u = __builtin_amdgcn_mfma_f32_16x16x32_bf16(a[mf][3], b3, u, 0, 0, 0);
      #pragma unroll
      for (int r = 0; r < 4; ++r)
        msg[mf][r] += xv[r] * (u[r] + bv);
    }
  }
  // scatter-add: row = e0 + mf*16 + hi*4 + r, col = wv*16 + lo
  const int col = wv * 16 + lo;
  #pragma unroll
  for (int mf = 0; mf < 4; ++mf) {
    int lrow = mf * 16 + hi * 4;
    #pragma unroll
    for (int r = 0; r < 4; ++r) {
      int ge = e0 + lrow + r;
      if (ge < N_EDGES)
        atomicAdd(agg + (size_t)s_dst[lrow + r] * 64 + col, msg[mf][r]);
    }
  }
}

// Node update: TWO nodes per wave, lane = output dim.
// m = lrelu(agg/denom + out@conv_root + cbias); GRU(h=out) -> out_next.
// Re-zeroes agg for the next step's atomics.
__global__ __launch_bounds__(256) void k_node(float* __restrict__ agg,
    const float* __restrict__ cnt, const float* __restrict__ out_cur,
    const float* __restrict__ cr,        // conv_root [i][o], o contiguous
    const float* __restrict__ cbias,
    const float* __restrict__ wihT, const float* __restrict__ whhT,
    const float* __restrict__ bih, const float* __restrict__ bhh,
    float* __restrict__ out_next) {
  __shared__ float s_h[4][2][64];
  __shared__ float s_m[4][2][64];
  const int w = threadIdx.x >> 6, o = threadIdx.x & 63;
  const int nd0 = blockIdx.x * 8 + w * 2;     // 1250 blocks * 8 = 10000 exact
  const int nd1 = nd0 + 1;
  const float hv0 = out_cur[(size_t)nd0 * 64 + o];
  const float hv1 = out_cur[(size_t)nd1 * 64 + o];
  s_h[w][0][o] = hv0;
  s_h[w][1][o] = hv1;
  float a0 = agg[(size_t)nd0 * 64 + o] / fmaxf(cnt[nd0], 1.f) + cbias[o];
  float a1 = agg[(size_t)nd1 * 64 + o] / fmaxf(cnt[nd1], 1.f) + cbias[o];
  agg[(size_t)nd0 * 64 + o] = 0.f;
  agg[(size_t)nd1 * 64 + o] = 0.f;
  __syncthreads();
  #pragma unroll 4
  for (int i = 0; i < 64; ++i) {
    float cv = cr[i * 64 + o];
    a0 += s_h[w][0][i] * cv;
    a1 += s_h[w][1][i] * cv;
  }
  s_m[w][0][o] = lrelu(a0);
  s_m[w][1][o] = lrelu(a1);
  __syncthreads();
  float gi0a = bih[o],       gh0a = bhh[o];
  float gi1a = bih[64 + o],  gh1a = bhh[64 + o];
  float gi2a = bih[128 + o], gh2a = bhh[128 + o];
  float gi0b = gi0a, gh0b = gh0a, gi1b = gi1a, gh1b = gh1a, gi2b = gi2a, gh2b = gh2a;
  #pragma unroll 4
  for (int i = 0; i < 64; ++i) {
    int io = i * 64 + o;
    float wi0 = wihT[io], wi1 = wihT[4096 + io], wi2 = wihT[8192 + io];
    float wh0 = whhT[io], wh1 = whhT[4096 + io], wh2 = whhT[8192 + io];
    float m0v = s_m[w][0][i], hva = s_h[w][0][i];
    float m1v = s_m[w][1][i], hvb = s_h[w][1][i];
    gi0a += m0v * wi0; gh0a += hva * wh0;
    gi1a += m0v * wi1; gh1a += hva * wh1;
    gi2a += m0v * wi2; gh2a += hva * wh2;
    gi0b += m1v * wi0; gh0b += hvb * wh0;
    gi1b += m1v * wi1; gh1b += hvb * wh1;
    gi2b += m1v * wi2; gh2b += hvb * wh2;
  }
  {
    float r_ = sigm(gi0a + gh0a);
    float z_ = sigm(gi1a + gh1a);
    float cand = tanhf(gi2a + r_ * gh2a);
    out_next[(size_t)nd0 * 64 + o] = (1.f - z_) * cand + z_ * hv0;
  }
  {
    float r_ = sigm(gi0b + gh0b);
    float z_ = sigm(gi1b + gh1b);
    float cand = tanhf(gi2b + r_ * gh2b);
    out_next[(size_t)nd1 * 64 + o] = (1.f - z_) * cand + z_ * hv1;
  }
}

// Set2Set + final linear: one block per graph (50 contiguous nodes).
__global__ __launch_bounds__(256) void k_s2s(const float* __restrict__ out,
    const float* __restrict__ wih, const float* __restrict__ whh,
    const float* __restrict__ bih, const float* __restrict__ bhh,
    const float* __restrict__ l1w, const float* __restrict__ l1b,
    float* __restrict__ dout) {
  __shared__ float s_out[NPG * 64];
  __shared__ float s_q[128];
  __shared__ float s_hs[64];
  __shared__ float s_cs[64];
  __shared__ float s_g[256];
  __shared__ float s_e[64];
  __shared__ float s_a[64];
  __shared__ float s_r[4][64];
  const int gb = blockIdx.x, tid = threadIdx.x;
  for (int t = tid; t < NPG * 64; t += 256)
    s_out[t] = out[(size_t)gb * NPG * 64 + t];
  if (tid < 128) s_q[tid] = 0.f;
  if (tid < 64) { s_hs[tid] = 0.f; s_cs[tid] = 0.f; }
  __syncthreads();
  for (int it = 0; it < S2S_STEPS; ++it) {
    float acc = bih[tid] + bhh[tid];
    const float* wi = wih + tid * 128;
    #pragma unroll 8
    for (int j = 0; j < 128; ++j) acc += s_q[j] * wi[j];
    const float* wh = whh + tid * 64;
    #pragma unroll 8
    for (int j = 0; j < 64; ++j) acc += s_hs[j] * wh[j];
    s_g[tid] = acc;
    __syncthreads();
    if (tid < 64) {
      float i_ = s_g[tid], f_ = s_g[64 + tid], g_ = s_g[128 + tid], o_ = s_g[192 + tid];
      float cs = sigm(f_) * s_cs[tid] + sigm(i_) * tanhf(g_);
      s_cs[tid] = cs;
      s_hs[tid] = sigm(o_) * tanhf(cs);
    }
    __syncthreads();
    {
      int wvi = tid >> 6, ln = tid & 63;
      for (int node = wvi; node < NPG; node += 4) {
        float p = s_out[node * 64 + ln] * s_hs[ln];
        #pragma unroll
        for (int m = 32; m; m >>= 1) p += __shfl_xor(p, m, 64);
        if (ln == 0) s_e[node] = p;
      }
    }
    __syncthreads();
    if (tid < 64) {
      float e = (tid < NPG) ? s_e[tid] : -1e30f;
      float mx = e;
      #pragma unroll
      for (int m = 32; m; m >>= 1) mx = fmaxf(mx, __shfl_xor(mx, m, 64));
      float a = (tid < NPG) ? expf(e - mx) : 0.f;
      float su = a;
      #pragma unroll
      for (int m = 32; m; m >>= 1) su += __shfl_xor(su, m, 64);
      s_a[tid] = a / su;
    }
    __syncthreads();
    {
      int wvi = tid >> 6, ln = tid & 63;
      float r = 0.f;
      for (int n2 = wvi; n2 < NPG; n2 += 4) r += s_a[n2] * s_out[n2 * 64 + ln];
      s_r[wvi][ln] = r;
    }
    __syncthreads();
    if (tid < 64) {
      s_q[64 + tid] = s_r[0][tid] + s_r[1][tid] + s_r[2][tid] + s_r[3][tid];
      s_q[tid] = s_hs[tid];
    }
    __syncthreads();
  }
  if (tid < 128) s_g[tid] = s_q[tid] * l1w[tid];
  __syncthreads();
  if (tid == 0) {
    float sm = 0.f;
    for (int j = 0; j < 128; ++j) sm += s_g[j];
    dout[gb] = sm + l1b[0];
  }
}

extern "C" void kernel_launch(void* const* d_in, const int* in_sizes, int n_in,
                              void* d_out, int out_size, void* d_ws, size_t ws_size,
                              hipStream_t stream) {
  (void)in_sizes; (void)n_in; (void)out_size; (void)ws_size;
  const float* x         = (const float*)d_in[0];
  const float* edge_attr = (const float*)d_in[1];
  const float* lin0_w    = (const float*)d_in[2];
  const float* lin0_b    = (const float*)d_in[3];
  const float* enet_w1   = (const float*)d_in[4];
  const float* enet_b1   = (const float*)d_in[5];
  const float* enet_w2   = (const float*)d_in[6];
  const float* enet_b2   = (const float*)d_in[7];
  const float* conv_root = (const float*)d_in[8];
  const float* conv_bias = (const float*)d_in[9];
  const float* gru_w_ih  = (const float*)d_in[10];
  const float* gru_w_hh  = (const float*)d_in[11];
  const float* gru_b_ih  = (const float*)d_in[12];
  const float* gru_b_hh  = (const float*)d_in[13];
  const float* s2s_w_ih  = (const float*)d_in[14];
  const float* s2s_w_hh  = (const float*)d_in[15];
  const float* s2s_b_ih  = (const float*)d_in[16];
  const float* s2s_b_hh  = (const float*)d_in[17];
  const float* lin1_w    = (const float*)d_in[18];
  const float* lin1_b    = (const float*)d_in[19];
  const int* edge_index  = (const int*)d_in[20];
  const int* srcp = edge_index;
  const int* dstp = edge_index + N_EDGES;

  char* ws = (char*)d_ws;
  size_t off = 0;
  auto carve = [&](size_t bytes) -> void* {
    void* p = ws + off;
    off += (bytes + 255) & ~(size_t)255;
    return p;
  };
  u16*   h1    = (u16*)carve((size_t)20032 * 128 * 2);      // padded rows
  u16*   W2T   = (u16*)carve((size_t)64 * 64 * 128 * 2);    // 1 MB
  float* wihT  = (float*)carve(3 * 64 * 64 * 4);
  float* whhT  = (float*)carve(3 * 64 * 64 * 4);
  float* out_a = (float*)carve((size_t)N_NODES * 64 * 4);
  float* out_b = (float*)carve((size_t)N_NODES * 64 * 4);
  float* aggb  = (float*)carve((size_t)N_NODES * 64 * 4);
  float* cnt   = (float*)carve(N_NODES * 4);

  hipMemsetAsync(cnt, 0, N_NODES * 4, stream);
  hipMemsetAsync(aggb, 0, (size_t)N_NODES * 64 * 4, stream);
  k_prep_all<<<12691, 256, 0, stream>>>(
      x, lin0_w, lin0_b, out_a,
      edge_attr, enet_w1, enet_b1, h1,
      enet_w2, gru_w_ih, gru_w_hh, W2T, wihT, whhT,
      dstp, cnt);

  float* cur = out_a;
  float* nxt = out_b;
  for (int s = 0; s < STEPS; ++s) {
    k_msgemm<<<(N_EDGES + 63) / 64, 256, 0, stream>>>(h1, W2T, enet_b2, cur,
        srcp, dstp, aggb);
    k_node<<<N_NODES / 8, 256, 0, stream>>>(aggb, cnt, cur, conv_root, conv_bias,
        wihT, whhT, gru_b_ih, gru_b_hh, nxt);
    float* t = cur; cur = nxt; nxt = t;
  }
  k_s2s<<<NB, 256, 0, stream>>>(cur, s2s_w_ih, s2s_w_hh, s2s_b_ih, s2s_b_hh,
      lin1_w, lin1_b, (float*)d_out);
}